// Round 11
// baseline (773.807 us; speedup 1.0000x reference)
//
#include <hip/hip_runtime.h>
#include <cstdint>
#include <cstddef>

using u16 = unsigned short;
using bf16x8 = __attribute__((ext_vector_type(8))) __bf16;
using f32x4  = __attribute__((ext_vector_type(4))) float;

constexpr int Bb = 2, Tt = 4096, Cc = 2048, Hh = 16, Dd = 128;
constexpr int Mm = Bb * Tt;   // 8192 rows
constexpr int CHK = 32;       // scan chunk length
constexpr int NCH = Tt / CHK; // 128 chunks per (b,h)
constexpr float EPSf = 1e-5f;

__device__ __forceinline__ u16 f2bf(float f) {
  union { float f; uint32_t u; } v; v.f = f;
  return (u16)((v.u + 0x7fffu + ((v.u >> 16) & 1u)) >> 16);  // RNE
}
__device__ __forceinline__ float bf2f(u16 h) {
  union { uint32_t u; float f; } v; v.u = ((uint32_t)h) << 16;
  return v.f;
}
__device__ __forceinline__ float sig_(float z) { return 1.f / (1.f + __expf(-z)); }
__device__ __forceinline__ float wred(float v) {
#pragma unroll
  for (int m = 32; m; m >>= 1) v += __shfl_xor(v, m);
  return v;
}
// 32-lane-group reduce (xor masks <=16 never cross the half-wave boundary)
__device__ __forceinline__ float wred32(float v) {
#pragma unroll
  for (int m = 16; m; m >>= 1) v += __shfl_xor(v, m);
  return v;
}
__device__ __forceinline__ void glds16(const u16* g, u16* l) {
  __builtin_amdgcn_global_load_lds(
      (const __attribute__((address_space(1))) unsigned int*)g,
      (__attribute__((address_space(3))) unsigned int*)l, 16, 0, 0);
}
// raw barrier with compiler-level memory pin (no auto vmcnt/lgkmcnt drain)
__device__ __forceinline__ void bar_() { asm volatile("s_barrier" ::: "memory"); }

// ---------------- conv (causal depthwise K=4) + silu + bf16 casts ----------
__global__ void la_conv(const float* __restrict__ x, const float* __restrict__ cw,
                        const float* __restrict__ cb, u16* __restrict__ xbf,
                        u16* __restrict__ xconv) {
  int i4 = blockIdx.x * 256 + threadIdx.x;         // < Mm*Cc/4
  int c4 = i4 & (Cc / 4 - 1);
  int bt = i4 >> 9;                                // /(Cc/4)
  int t = bt & (Tt - 1);
  const float4* x4 = (const float4*)x;
  float4 xv = x4[i4];
  float4 xm1 = t >= 1 ? x4[i4 - Cc / 4] : make_float4(0, 0, 0, 0);
  float4 xm2 = t >= 2 ? x4[i4 - Cc / 2] : make_float4(0, 0, 0, 0);
  float4 xm3 = t >= 3 ? x4[i4 - 3 * Cc / 4] : make_float4(0, 0, 0, 0);
  ushort4 ob; ushort4 oc;
  const float4* cw4 = (const float4*)cw;
  float vv[4]  = {xv.x, xv.y, xv.z, xv.w};
  float v1[4]  = {xm1.x, xm1.y, xm1.z, xm1.w};
  float v2[4]  = {xm2.x, xm2.y, xm2.z, xm2.w};
  float v3[4]  = {xm3.x, xm3.y, xm3.z, xm3.w};
  u16 rb[4], rc[4];
#pragma unroll
  for (int j = 0; j < 4; j++) {
    int c = c4 * 4 + j;
    float4 w = cw4[c];
    float acc = cb[c] + w.w * vv[j] + w.z * v1[j] + w.y * v2[j] + w.x * v3[j];
    rb[j] = f2bf(vv[j]);
    rc[j] = f2bf(acc * sig_(acc));
  }
  ob.x = rb[0]; ob.y = rb[1]; ob.z = rb[2]; ob.w = rb[3];
  oc.x = rc[0]; oc.y = rc[1]; oc.z = rc[2]; oc.w = rc[3];
  ((ushort4*)xbf)[i4] = ob;
  ((ushort4*)xconv)[i4] = oc;
}

// ---------------- fp32 -> bf16 convert: 5 weights in one dispatch ----------
__global__ void la_cvt5(const float* w0, const float* w1, const float* w2,
                        const float* w3, const float* w4,
                        u16* o0, u16* o1, u16* o2, u16* o3, u16* o4, int n4each) {
  int i = blockIdx.x * 256 + threadIdx.x;
  int seg = i / n4each;                            // block-uniform
  int off = i - seg * n4each;
  const float* src = seg == 0 ? w0 : seg == 1 ? w1 : seg == 2 ? w2 : seg == 3 ? w3 : w4;
  u16* dst = seg == 0 ? o0 : seg == 1 ? o1 : seg == 2 ? o2 : seg == 3 ? o3 : o4;
  float4 v = ((const float4*)src)[off];
  ushort4 o;
  o.x = f2bf(v.x); o.y = f2bf(v.y); o.z = f2bf(v.z); o.w = f2bf(v.w);
  ((ushort4*)dst)[off] = o;
}

// ---------------- gamma = sigmoid(xconv @ Wgam.T + bgam) + Wo bf16 cvt -----
__global__ __launch_bounds__(256) void la_gamma(
    const u16* __restrict__ xconv, const float* __restrict__ Wg,
    const float* __restrict__ bg, float* __restrict__ gam,
    const float* __restrict__ wo_src, u16* __restrict__ wo_dst) {
  {
    int base = blockIdx.x * 2048;                  // 512 blocks x 2048 = Cc*Cc/4
    for (int i = threadIdx.x; i < 2048; i += 256) {
      float4 v = ((const float4*)wo_src)[base + i];
      ushort4 o;
      o.x = f2bf(v.x); o.y = f2bf(v.y); o.z = f2bf(v.z); o.w = f2bf(v.w);
      ((ushort4*)wo_dst)[base + i] = o;
    }
  }
  __shared__ u16 wlds[Hh * Cc];                    // 64 KB
  for (int i = threadIdx.x; i < Hh * Cc / 4; i += 256) {
    float4 v = ((const float4*)Wg)[i];
    ushort4 o;
    o.x = f2bf(v.x); o.y = f2bf(v.y); o.z = f2bf(v.z); o.w = f2bf(v.w);
    ((ushort4*)wlds)[i] = o;
  }
  __syncthreads();
  const int wave = threadIdx.x >> 6, lane = threadIdx.x & 63;
  const int row0 = blockIdx.x * 16 + wave * 4;
#pragma unroll
  for (int r = 0; r < 4; r++) {
    const int row = row0 + r;
    const u16* xr = xconv + (size_t)row * Cc + lane * 8;
    bf16x8 xv[4];
#pragma unroll
    for (int it = 0; it < 4; it++) xv[it] = *(const bf16x8*)(xr + it * 512);
#pragma unroll
    for (int h = 0; h < 16; h++) {
      const u16* wr = wlds + h * Cc + lane * 8;
      float acc = 0.f;
#pragma unroll
      for (int it = 0; it < 4; it++) {
        bf16x8 wv = *(const bf16x8*)(wr + it * 512);
#pragma unroll
        for (int e = 0; e < 8; e++) acc += (float)xv[it][e] * (float)wv[e];
      }
      acc = wred(acc);
      if (lane == 0) gam[row * Hh + h] = sig_(acc + bg[h]);
    }
  }
}

// ---------------- scan phase 1 (FUSED prep, WIDENED 8 B/lane): each 32-lane
// half-wave owns one (b,h,chunk); 4 elems/lane; uint2 loads/stores; 32-wide
// reduces. Serial t-chain unchanged (loads batched 8 rows deep).
// mem written in-place over pk (same buffer; per-row read precedes write
// within the single owning half-wave).
__global__ void la_scan1(const u16* pk, const u16* __restrict__ pv,
                         const u16* __restrict__ pig,
                         const float* __restrict__ vng, const float* __restrict__ vnb,
                         const float* __restrict__ bigv,
                         u16* mem, float* gam, float* __restrict__ Ebuf) {
  const int sub  = threadIdx.x >> 5;             // 0..7 half-waves
  const int lane = threadIdx.x & 31;
  const int p = blockIdx.x * 8 + sub;            // < Bb*Hh*NCH
  const int bh = p >> 7, c = p & (NCH - 1);
  const int b = bh >> 4, h = bh & 15;
  const int t0 = c * CHK;
  const size_t rbase = (size_t)b * Tt + t0;
  const int d0 = lane * 4;
  const int c0 = h * Dd + d0;
  const size_t base = rbase * Cc + c0;
  float* gp = gam + rbase * Hh + h;
  const float4 vg = *(const float4*)&vng[d0];
  const float4 vb = *(const float4*)&vnb[d0];
  const float4 bg = *(const float4*)&bigv[c0];
  float m0 = 0.f, m1 = 0.f, m2 = 0.f, m3 = 0.f, cg = 1.f;
  for (int tb = 0; tb < CHK; tb += 8) {
    uint2 uk[8], uv[8], ui[8]; float g[8];
#pragma unroll
    for (int j = 0; j < 8; j++) {
      size_t bb = base + (size_t)(tb + j) * Cc;
      uk[j] = *(const uint2*)(pk + bb);
      uv[j] = *(const uint2*)(pv + bb);
      ui[j] = *(const uint2*)(pig + bb);
      g[j] = gp[(size_t)(tb + j) * Hh];
    }
#pragma unroll
    for (int j = 0; j < 8; j++) {
      float k0 = bf2f((u16)uk[j].x), k1 = bf2f((u16)(uk[j].x >> 16));
      float k2 = bf2f((u16)uk[j].y), k3 = bf2f((u16)(uk[j].y >> 16));
      float v0 = bf2f((u16)uv[j].x), v1 = bf2f((u16)(uv[j].x >> 16));
      float v2 = bf2f((u16)uv[j].y), v3 = bf2f((u16)(uv[j].y >> 16));
      float i0 = bf2f((u16)ui[j].x), i1 = bf2f((u16)(ui[j].x >> 16));
      float i2 = bf2f((u16)ui[j].y), i3 = bf2f((u16)(ui[j].y >> 16));
      float ks = k0*k0 + k1*k1 + k2*k2 + k3*k3;
      float s1 = v0 + v1 + v2 + v3;
      float s2 = v0*v0 + v1*v1 + v2*v2 + v3*v3;
#pragma unroll
      for (int m = 16; m; m >>= 1) {
        ks += __shfl_xor(ks, m);
        s1 += __shfl_xor(s1, m);
        s2 += __shfl_xor(s2, m);
      }
      float kn = 1.f / fmaxf(sqrtf(ks), 1e-12f);
      float mu = s1 * (1.f / Dd);
      float var = s2 * (1.f / Dd) - mu * mu;
      float rs = rsqrtf(var + EPSf);
      float vh0 = (v0 - mu) * rs * vg.x + vb.x;
      float vh1 = (v1 - mu) * rs * vg.y + vb.y;
      float vh2 = (v2 - mu) * rs * vg.z + vb.z;
      float vh3 = (v3 - mu) * rs * vg.w + vb.w;
      float kv0 = sig_(i0 + bg.x) * (k0 * kn) * vh0;
      float kv1 = sig_(i1 + bg.y) * (k1 * kn) * vh1;
      float kv2 = sig_(i2 + bg.z) * (k2 * kn) * vh2;
      float kv3 = sig_(i3 + bg.w) * (k3 * kn) * vh3;
      float gg = g[j];
      cg *= gg;
      m0 = fmaf(gg, m0, kv0);
      m1 = fmaf(gg, m1, kv1);
      m2 = fmaf(gg, m2, kv2);
      m3 = fmaf(gg, m3, kv3);
      size_t bb = base + (size_t)(tb + j) * Cc;
      uint2 om;
      om.x = (uint32_t)f2bf(m0) | ((uint32_t)f2bf(m1) << 16);
      om.y = (uint32_t)f2bf(m2) | ((uint32_t)f2bf(m3) << 16);
      *(uint2*)(mem + bb) = om;
      if (lane == 0) gp[(size_t)(tb + j) * Hh] = cg;   // cumgamma from chunk start
    }
  }
  float4 e; e.x = m0; e.y = m1; e.z = m2; e.w = m3;
  *(float4*)&Ebuf[(size_t)p * Dd + d0] = e;
}

// ---------------- scan phase 2: carry across chunks (loads batched 8) ------
__global__ void la_scan2(const float* __restrict__ Ebuf, const float* __restrict__ cumg,
                         float* __restrict__ carry) {
  const int bh = blockIdx.x;
  const int b = bh >> 4, h = bh & 15;
  const int lane = threadIdx.x;
  float S0 = 0.f, S1 = 0.f;
  for (int cb = 0; cb < NCH; cb += 8) {
    float2 E[8]; float P[8];
#pragma unroll
    for (int j = 0; j < 8; j++) {
      size_t idx = ((size_t)bh * NCH + cb + j) * Dd + lane * 2;
      E[j] = *(const float2*)&Ebuf[idx];
      P[j] = cumg[((size_t)b * Tt + (cb + j) * CHK + CHK - 1) * Hh + h];
    }
#pragma unroll
    for (int j = 0; j < 8; j++) {
      size_t idx = ((size_t)bh * NCH + cb + j) * Dd + lane * 2;
      float2 s; s.x = S0; s.y = S1;
      *(float2*)&carry[idx] = s;                 // carry INTO chunk cb+j
      S0 = fmaf(P[j], S0, E[j].x);
      S1 = fmaf(P[j], S1, E[j].y);
    }
  }
}

// ---------------- post (widened, 8-16 B/lane; R10-proven) ------------------
__global__ void la_post(const u16* mem, const u16* qp, const u16* ogp,
                        const float* __restrict__ cumg, const float* __restrict__ carry,
                        const float* __restrict__ mng, const float* __restrict__ mnb,
                        const float* __restrict__ gng, const float* __restrict__ gnb,
                        const float* __restrict__ bog, u16* outb) {
  const int wave = threadIdx.x >> 6, lane = threadIdx.x & 63;
  const int p2 = blockIdx.x * 4 + wave;          // < Mm*8
  const int row = p2 >> 3, h2 = p2 & 7;
  const int h = h2 * 2 + (lane >> 5);
  const int b = row >> 12, t = row & (Tt - 1), ch = t >> 5;  // CHK=32
  const int d0 = (lane & 31) * 4;
  const int c0 = h * Dd + d0;
  const size_t base = (size_t)row * Cc + c0;
  uint2 um = *(const uint2*)(mem + base);
  uint2 uq = *(const uint2*)(qp + base);
  uint2 uo = *(const uint2*)(ogp + base);
  float cg = cumg[(size_t)row * Hh + h];
  float4 cr = *(const float4*)&carry[(((size_t)(b * Hh + h)) * NCH + ch) * Dd + d0];
  float m0 = fmaf(cg, cr.x, bf2f((u16)um.x));
  float m1 = fmaf(cg, cr.y, bf2f((u16)(um.x >> 16)));
  float m2 = fmaf(cg, cr.z, bf2f((u16)um.y));
  float m3 = fmaf(cg, cr.w, bf2f((u16)(um.y >> 16)));
  float q0 = bf2f((u16)uq.x), q1 = bf2f((u16)(uq.x >> 16));
  float q2 = bf2f((u16)uq.y), q3 = bf2f((u16)(uq.y >> 16));
  float g0 = bf2f((u16)uo.x), g1 = bf2f((u16)(uo.x >> 16));
  float g2 = bf2f((u16)uo.y), g3 = bf2f((u16)(uo.y >> 16));
  float qs = wred32(q0*q0 + q1*q1 + q2*q2 + q3*q3);
  float s1 = wred32(m0 + m1 + m2 + m3);
  float s2 = wred32(m0*m0 + m1*m1 + m2*m2 + m3*m3);
  float qn = 1.f / fmaxf(sqrtf(qs), 1e-12f);
  float mu = s1 * (1.f / Dd);
  float var = s2 * (1.f / Dd) - mu * mu;
  float rs = rsqrtf(var + EPSf);
  float4 mg = *(const float4*)&mng[d0];
  float4 mb = *(const float4*)&mnb[d0];
  float o0 = ((m0 - mu) * rs * mg.x + mb.x) * q0 * qn;
  float o1 = ((m1 - mu) * rs * mg.y + mb.y) * q1 * qn;
  float o2 = ((m2 - mu) * rs * mg.z + mb.z) * q2 * qn;
  float o3 = ((m3 - mu) * rs * mg.w + mb.w) * q3 * qn;
  float t1 = wred32(o0 + o1 + o2 + o3);
  float t2 = wred32(o0*o0 + o1*o1 + o2*o2 + o3*o3);
  float mu2 = t1 * (1.f / Dd);
  float var2 = t2 * (1.f / Dd) - mu2 * mu2;
  float rs2 = rsqrtf(var2 + EPSf);
  float4 gg = *(const float4*)&gng[c0];
  float4 gb = *(const float4*)&gnb[c0];
  float4 bo = *(const float4*)&bog[c0];
  float y0 = ((o0 - mu2) * rs2 * gg.x + gb.x) * sig_(g0 + bo.x);
  float y1 = ((o1 - mu2) * rs2 * gg.y + gb.y) * sig_(g1 + bo.y);
  float y2 = ((o2 - mu2) * rs2 * gg.z + gb.z) * sig_(g2 + bo.z);
  float y3 = ((o3 - mu2) * rs2 * gg.w + gb.w) * sig_(g3 + bo.w);
  uint2 out;
  out.x = (uint32_t)f2bf(y0) | ((uint32_t)f2bf(y1) << 16);
  out.y = (uint32_t)f2bf(y2) | ((uint32_t)f2bf(y3) << 16);
  *(uint2*)(outb + base) = out;
}

// ---------------- GEMM: C = A @ W^T, 256x256 tile, BK=32, pipelined 4-phase
// R2 phase topology unchanged; BK 64->32 shrinks LDS 128->64 KB so TWO
// blocks co-reside per CU (VGPR=128 already allows 4 waves/SIMD). Block A's
// barrier-locked MFMA phases overlap block B's LDS phases (m114 mechanism) —
// attacks the measured MFMA+LDS serialization (2480+2800 cyc/tile = wall).
// Slots 8 KB: s0=A[0,128), s1=W[128,256), s2=A[128,256), s3=W[0,128).
// 4-granule swizzle (re-derived, 2 lanes/bank = free):
//   store: thread covers row wv*16+(l>>2), granule slot l&3 holds global
//          granule (l&3)^((l>>3)&3)  [inverse of (row>>1)&3 XOR]
//   read:  granule pos = (lane>>4) ^ ((fm>>1)&3)
// vmcnt (1 glds/thread/stage): prologue 7 stages -> vmcnt(3); per-tile gate
// at ph2-end vmcnt(2) (drains all of tile kt+1); vmcnt(0) at kt==nkt-2.
// WAR topology identical to R2 (slots overwritten >=1 barrier after reads).
#define STAGE(t, j) do {                                                        \
    const u16* _s = (((j) == 0 || (j) == 2) ? Ab : Wb)                          \
                    + (((j) == 1 || (j) == 2) ? (size_t)128 * K : (size_t)0)    \
                    + soff + (size_t)(t) * 32;                                  \
    glds16(_s, dbase + ((((t) & 1) * 4 + (j)) * 4096));                         \
  } while (0)

#define LDFRAG(DST, NFR, SLOT, RBASE) do {                                      \
    _Pragma("unroll")                                                           \
    for (int _i = 0; _i < (NFR); ++_i)                                          \
      DST[_i] = *(const bf16x8*)&(SLOT)[((RBASE) + _i * 16) * 32 +              \
                   (((lane >> 4) ^ x3) * 8)];                                   \
  } while (0)

#define MM8(QM, QN, AA, BB) do {                                                \
    __builtin_amdgcn_s_setprio(1);                                              \
    _Pragma("unroll")                                                           \
    for (int _mi = 0; _mi < 4; ++_mi)                                           \
      _Pragma("unroll")                                                         \
      for (int _ni = 0; _ni < 2; ++_ni)                                         \
        acc[QM][QN][_mi][_ni] = __builtin_amdgcn_mfma_f32_16x16x32_bf16(        \
            AA[_mi], BB[_ni], acc[QM][QN][_mi][_ni], 0, 0, 0);                  \
    __builtin_amdgcn_s_setprio(0);                                              \
  } while (0)

#define MM8_ARD(QM, QN, AA, BB, RSLOT) do {                                     \
    __builtin_amdgcn_s_setprio(1);                                              \
    _Pragma("unroll")                                                           \
    for (int _mi = 0; _mi < 4; ++_mi) {                                         \
      _Pragma("unroll")                                                         \
      for (int _ni = 0; _ni < 2; ++_ni)                                         \
        acc[QM][QN][_mi][_ni] = __builtin_amdgcn_mfma_f32_16x16x32_bf16(        \
            AA[_mi], BB[_ni], acc[QM][QN][_mi][_ni], 0, 0, 0);                  \
      AA[_mi] = *(const bf16x8*)&(RSLOT)[((ra) + _mi * 16) * 32 +               \
                   (((lane >> 4) ^ x3) * 8)];                                   \
    }                                                                           \
    __builtin_amdgcn_s_setprio(0);                                              \
  } while (0)

template <int OUT_BF16>
__global__ __launch_bounds__(512, 2)
void la_gemm(const u16* __restrict__ A0, const u16* __restrict__ A1, int segA2,
             const u16* __restrict__ W0, const u16* __restrict__ W1,
             const u16* __restrict__ W2, const u16* __restrict__ W3,
             const u16* __restrict__ W4,
             void* __restrict__ C0, void* __restrict__ C1, void* __restrict__ C2,
             void* __restrict__ C3, void* __restrict__ C4, int K) {
  __shared__ u16 lds[8 * 4096];   // 64 KB -> 2 blocks/CU
  const int tid  = threadIdx.x;
  const int lane = tid & 63;
  const int wv   = tid >> 6;      // 0..7
  const int wm = wv >> 2;         // 0..1  (M)
  const int wn = wv & 3;          // 0..3  (N)
  const int fm = lane & 15;
  const int x3 = (fm >> 1) & 3;
  const int seg = blockIdx.x >> 3;
  const int bn = (blockIdx.x & 7) * 256;
  const int bm = blockIdx.y * 256;
  const u16* W = seg == 0 ? W0 : seg == 1 ? W1 : seg == 2 ? W2 : seg == 3 ? W3 : W4;
  void* Co = seg == 0 ? C0 : seg == 1 ? C1 : seg == 2 ? C2 : seg == 3 ? C3 : C4;
  const u16* A = seg < segA2 ? A0 : A1;

  const u16* Ab = A + (size_t)bm * K;
  const u16* Wb = W + (size_t)bn * K;
  // staging: wave covers rows [wv*16, wv*16+16), 4 lanes/row, pre-swizzled
  // global granule = (l&3) ^ ((l>>3)&3)
  const size_t soff = (size_t)(wv * 16 + (lane >> 2)) * K
                      + (size_t)((((lane & 3) ^ ((lane >> 3) & 3))) * 8);
  u16* const dbase = lds + wv * 512;    // wave-uniform; HW adds lane*16B
  const int nkt = K >> 5;               // 64 for K=2048
  const int ra = wm * 64 + fm;          // A row within half (per quadrant)
  const int rb = wn * 32 + fm;          // W row within half

  f32x4 acc[2][2][4][2] = {};
  bf16x8 af[4], b0f[2], b1f[2];

  // prologue: tile0 all 4 half-tiles, then tile1 slots {2,1,3}
  STAGE(0, 0); STAGE(0, 1); STAGE(0, 2); STAGE(0, 3);
  __builtin_amdgcn_sched_barrier(0);    // keep tile0's 4 loads oldest
  STAGE(1, 2); STAGE(1, 1); STAGE(1, 3);
  asm volatile("s_waitcnt vmcnt(3)" ::: "memory");   // tile0 landed
  bar_();
  // pre-reads ("kt=-1 ph3"): b1 <- (t0,slot1); a <- (t0,slot2) = a1
  LDFRAG(b1f, 2, lds + 1 * 4096, rb);
  LDFRAG(af, 4, lds + 2 * 4096, ra);

  for (int kt = 0; kt < nkt; ++kt) {
    u16* const cur = lds + (kt & 1) * 4 * 4096;
    u16* const nxt = lds + ((kt & 1) ^ 1) * 4 * 4096;

    // ph0: q11 = (a1, b1); read b0 <- cur slot3; stage (kt+1, 0)
    bar_();
    LDFRAG(b0f, 2, cur + 3 * 4096, rb);
    if (kt + 1 < nkt) STAGE(kt + 1, 0);
    __builtin_amdgcn_sched_barrier(0);
    MM8(1, 1, af, b1f);

    // ph1: q10 = (a1, b0); interleaved a <- cur slot0 (a0); stage (kt+2, 2)
    bar_();
    if (kt + 2 < nkt) STAGE(kt + 2, 2);
    __builtin_amdgcn_sched_barrier(0);
    MM8_ARD(1, 0, af, b0f, cur + 0 * 4096);

    // ph2: q01 = (a0, b1); stage (kt+2, 1); counted vmcnt gate for tile kt+1
    bar_();
    if (kt + 2 < nkt) STAGE(kt + 2, 1);
    __builtin_amdgcn_sched_barrier(0);
    MM8(0, 1, af, b1f);
    if (kt < nkt - 2)       asm volatile("s_waitcnt vmcnt(2)" ::: "memory");
    else if (kt == nkt - 2) asm volatile("s_waitcnt vmcnt(0)" ::: "memory");

    // ph3: q00 = (a0, b0); read b1 <- nxt slot1; interleaved a <- nxt slot2;
    //      stage (kt+2, 3)
    bar_();
    if (kt + 1 < nkt) {
      LDFRAG(b1f, 2, nxt + 1 * 4096, rb);
      if (kt + 2 < nkt) STAGE(kt + 2, 3);
      __builtin_amdgcn_sched_barrier(0);
      MM8_ARD(0, 0, af, b0f, nxt + 2 * 4096);
    } else {
      __builtin_amdgcn_sched_barrier(0);
      MM8(0, 0, af, b0f);
    }
  }

  const int cr = (lane >> 4) * 4;
  const int cc = lane & 15;
#pragma unroll
  for (int qm = 0; qm < 2; ++qm)
#pragma unroll
    for (int qn = 0; qn < 2; ++qn)
#pragma unroll
      for (int mi = 0; mi < 4; ++mi)
#pragma unroll
        for (int ni = 0; ni < 2; ++ni)
#pragma unroll
          for (int r = 0; r < 4; ++r) {
            size_t off = (size_t)(bm + qm * 128 + wm * 64 + mi * 16 + cr + r) * Cc
                         + (bn + qn * 128 + wn * 32 + ni * 16 + cc);
            if (OUT_BF16) ((u16*)Co)[off] = f2bf(acc[qm][qn][mi][ni][r]);
            else          ((float*)Co)[off] = acc[qm][qn][mi][ni][r];
          }
}

// ---------------- launcher -------------------------------------------------
extern "C" void kernel_launch(void* const* d_in, const int* in_sizes, int n_in,
                              void* d_out, int out_size, void* d_ws, size_t ws_size,
                              hipStream_t stream) {
  (void)in_sizes; (void)n_in; (void)out_size; (void)ws_size;
  const float* x    = (const float*)d_in[0];
  const float* Wq   = (const float*)d_in[1];
  const float* Wk   = (const float*)d_in[2];
  const float* Wv   = (const float*)d_in[3];
  const float* Wo   = (const float*)d_in[4];
  const float* cw   = (const float*)d_in[5];
  const float* cb   = (const float*)d_in[6];
  const float* Wig  = (const float*)d_in[7];
  const float* big  = (const float*)d_in[8];
  const float* Wog  = (const float*)d_in[9];
  const float* bog  = (const float*)d_in[10];
  const float* Wgam = (const float*)d_in[11];
  const float* bgam = (const float*)d_in[12];
  const float* vng  = (const float*)d_in[13];
  const float* vnb  = (const float*)d_in[14];
  const float* mng  = (const float*)d_in[15];
  const float* mnb  = (const float*)d_in[16];
  const float* gng  = (const float*)d_in[17];
  const float* gnb  = (const float*)d_in[18];

  char* ws = (char*)d_ws;
  const size_t NB = (size_t)Mm * Cc * 2;          // 32 MB per bf16 activation buf
  u16* xbf   = (u16*)(ws + 0 * NB);               // x bf16 -> post out
  u16* xconv = (u16*)(ws + 1 * NB);               // silu(conv) bf16
  u16* preq  = (u16*)(ws + 2 * NB);               // q_pre (normalized in post)
  u16* prek  = (u16*)(ws + 3 * NB);               // k_pre -> mem (scan1 in-place)
  u16* prev  = (u16*)(ws + 4 * NB);               // v_pre (dead after scan1)
  u16* preig = (u16*)(ws + 5 * NB);               // Wk,Wv,Wig,Wog bf16 -> E/carry
  u16* wbf   = (u16*)(ws + 6 * NB);               // Wq bf16 -> Wo bf16 (8 MB)
  float* gam = (float*)(ws + 6 * NB + (size_t)Cc * Cc * 2);  // [Mm][Hh] -> cumg
  const size_t WE = (size_t)Cc * Cc;
  u16* wk_bf  = preig;
  u16* wv_bf  = preig + WE;
  u16* wig_bf = preig + 2 * WE;
  u16* wog_bf = preig + 3 * WE;
  float* Ebuf  = (float*)preig;                   // 2 MB (weights dead by scan1)
  float* carry = (float*)(preig + 1024 * 1024);   // 2 MB at +2 MB
  // d_out (64 MB) as scratch until the final GEMM overwrites it:
  u16* ogscr = (u16*)d_out;                       // og_pre bf16 [0, 32 MB)
  u16* igscr = (u16*)((char*)d_out + NB);         // ig_pre bf16 [32, 64 MB)

  const int WN4 = Cc * Cc / 4;
  dim3 blk(256);
  dim3 gblk(512);

  la_conv<<<Mm * Cc / 4 / 256, blk, 0, stream>>>(x, cw, cb, xbf, xconv);

  la_cvt5<<<5 * WN4 / 256, blk, 0, stream>>>(Wq, Wk, Wv, Wig, Wog,
                                             wbf, wk_bf, wv_bf, wig_bf, wog_bf, WN4);

  // merged QKV + ig/og: 5 segments x 8 col-tiles = grid.x 40, 1280 blocks
  la_gemm<1><<<dim3(40, Mm / 256), gblk, 0, stream>>>(
      xbf, xconv, 3, wbf, wk_bf, wv_bf, wig_bf, wog_bf,
      (void*)preq, (void*)prek, (void*)prev, (void*)igscr, (void*)ogscr, Cc);

  // gamma + Wo bf16 conversion (Wq slot dead after merged GEMM)
  la_gamma<<<Mm / 16, blk, 0, stream>>>(xconv, Wgam, bgam, gam, Wo, wbf);

  // fused prep+scan1 (widened): reads prek/prev/igscr, writes mem into prek
  la_scan1<<<Bb * Hh * NCH / 8, blk, 0, stream>>>(prek, prev, igscr,
                                                  vng, vnb, big, prek, gam, Ebuf);
  la_scan2<<<Bb * Hh, dim3(64), 0, stream>>>(Ebuf, gam, carry);

  // widened post: 1 half-wave per (row, head), 4 elems/lane
  la_post<<<Mm * 8 / 4, blk, 0, stream>>>(prek, preq, ogscr, gam, carry,
                                          mng, mnb, gng, gnb, bog, xbf);

  la_gemm<0><<<dim3(8, Mm / 256), gblk, 0, stream>>>(
      xbf, xbf, 5, wbf, wbf, wbf, wbf, wbf,
      d_out, d_out, d_out, d_out, d_out, Cc);
}

// Round 12
// 707.877 us; speedup vs baseline: 1.0931x; 1.0931x over previous
//
#include <hip/hip_runtime.h>
#include <cstdint>
#include <cstddef>

using u16 = unsigned short;
using bf16x8 = __attribute__((ext_vector_type(8))) __bf16;
using f32x4  = __attribute__((ext_vector_type(4))) float;

constexpr int Bb = 2, Tt = 4096, Cc = 2048, Hh = 16, Dd = 128;
constexpr int Mm = Bb * Tt;   // 8192 rows
constexpr int CHK = 32;       // scan chunk length
constexpr int NCH = Tt / CHK; // 128 chunks per (b,h)
constexpr float EPSf = 1e-5f;

__device__ __forceinline__ u16 f2bf(float f) {
  union { float f; uint32_t u; } v; v.f = f;
  return (u16)((v.u + 0x7fffu + ((v.u >> 16) & 1u)) >> 16);  // RNE
}
__device__ __forceinline__ float bf2f(u16 h) {
  union { uint32_t u; float f; } v; v.u = ((uint32_t)h) << 16;
  return v.f;
}
__device__ __forceinline__ float sig_(float z) { return 1.f / (1.f + __expf(-z)); }
__device__ __forceinline__ float wred(float v) {
#pragma unroll
  for (int m = 32; m; m >>= 1) v += __shfl_xor(v, m);
  return v;
}
// 32-lane-group reduce (xor masks <=16 never cross the half-wave boundary)
__device__ __forceinline__ float wred32(float v) {
#pragma unroll
  for (int m = 16; m; m >>= 1) v += __shfl_xor(v, m);
  return v;
}
__device__ __forceinline__ void glds16(const u16* g, u16* l) {
  __builtin_amdgcn_global_load_lds(
      (const __attribute__((address_space(1))) unsigned int*)g,
      (__attribute__((address_space(3))) unsigned int*)l, 16, 0, 0);
}
// raw barrier with compiler-level memory pin (no auto vmcnt/lgkmcnt drain)
__device__ __forceinline__ void bar_() { asm volatile("s_barrier" ::: "memory"); }

// ---------------- conv (causal depthwise K=4) + silu + bf16 casts ----------
__global__ void la_conv(const float* __restrict__ x, const float* __restrict__ cw,
                        const float* __restrict__ cb, u16* __restrict__ xbf,
                        u16* __restrict__ xconv) {
  int i4 = blockIdx.x * 256 + threadIdx.x;         // < Mm*Cc/4
  int c4 = i4 & (Cc / 4 - 1);
  int bt = i4 >> 9;                                // /(Cc/4)
  int t = bt & (Tt - 1);
  const float4* x4 = (const float4*)x;
  float4 xv = x4[i4];
  float4 xm1 = t >= 1 ? x4[i4 - Cc / 4] : make_float4(0, 0, 0, 0);
  float4 xm2 = t >= 2 ? x4[i4 - Cc / 2] : make_float4(0, 0, 0, 0);
  float4 xm3 = t >= 3 ? x4[i4 - 3 * Cc / 4] : make_float4(0, 0, 0, 0);
  ushort4 ob; ushort4 oc;
  const float4* cw4 = (const float4*)cw;
  float vv[4]  = {xv.x, xv.y, xv.z, xv.w};
  float v1[4]  = {xm1.x, xm1.y, xm1.z, xm1.w};
  float v2[4]  = {xm2.x, xm2.y, xm2.z, xm2.w};
  float v3[4]  = {xm3.x, xm3.y, xm3.z, xm3.w};
  u16 rb[4], rc[4];
#pragma unroll
  for (int j = 0; j < 4; j++) {
    int c = c4 * 4 + j;
    float4 w = cw4[c];
    float acc = cb[c] + w.w * vv[j] + w.z * v1[j] + w.y * v2[j] + w.x * v3[j];
    rb[j] = f2bf(vv[j]);
    rc[j] = f2bf(acc * sig_(acc));
  }
  ob.x = rb[0]; ob.y = rb[1]; ob.z = rb[2]; ob.w = rb[3];
  oc.x = rc[0]; oc.y = rc[1]; oc.z = rc[2]; oc.w = rc[3];
  ((ushort4*)xbf)[i4] = ob;
  ((ushort4*)xconv)[i4] = oc;
}

// ---------------- fp32 -> bf16 convert: 5 weights in one dispatch ----------
__global__ void la_cvt5(const float* w0, const float* w1, const float* w2,
                        const float* w3, const float* w4,
                        u16* o0, u16* o1, u16* o2, u16* o3, u16* o4, int n4each) {
  int i = blockIdx.x * 256 + threadIdx.x;
  int seg = i / n4each;                            // block-uniform
  int off = i - seg * n4each;
  const float* src = seg == 0 ? w0 : seg == 1 ? w1 : seg == 2 ? w2 : seg == 3 ? w3 : w4;
  u16* dst = seg == 0 ? o0 : seg == 1 ? o1 : seg == 2 ? o2 : seg == 3 ? o3 : o4;
  float4 v = ((const float4*)src)[off];
  ushort4 o;
  o.x = f2bf(v.x); o.y = f2bf(v.y); o.z = f2bf(v.z); o.w = f2bf(v.w);
  ((ushort4*)dst)[off] = o;
}

// ---------------- gamma = sigmoid(xconv @ Wgam.T + bgam) + Wo bf16 cvt -----
__global__ __launch_bounds__(256) void la_gamma(
    const u16* __restrict__ xconv, const float* __restrict__ Wg,
    const float* __restrict__ bg, float* __restrict__ gam,
    const float* __restrict__ wo_src, u16* __restrict__ wo_dst) {
  {
    int base = blockIdx.x * 2048;                  // 512 blocks x 2048 = Cc*Cc/4
    for (int i = threadIdx.x; i < 2048; i += 256) {
      float4 v = ((const float4*)wo_src)[base + i];
      ushort4 o;
      o.x = f2bf(v.x); o.y = f2bf(v.y); o.z = f2bf(v.z); o.w = f2bf(v.w);
      ((ushort4*)wo_dst)[base + i] = o;
    }
  }
  __shared__ u16 wlds[Hh * Cc];                    // 64 KB
  for (int i = threadIdx.x; i < Hh * Cc / 4; i += 256) {
    float4 v = ((const float4*)Wg)[i];
    ushort4 o;
    o.x = f2bf(v.x); o.y = f2bf(v.y); o.z = f2bf(v.z); o.w = f2bf(v.w);
    ((ushort4*)wlds)[i] = o;
  }
  __syncthreads();
  const int wave = threadIdx.x >> 6, lane = threadIdx.x & 63;
  const int row0 = blockIdx.x * 16 + wave * 4;
#pragma unroll
  for (int r = 0; r < 4; r++) {
    const int row = row0 + r;
    const u16* xr = xconv + (size_t)row * Cc + lane * 8;
    bf16x8 xv[4];
#pragma unroll
    for (int it = 0; it < 4; it++) xv[it] = *(const bf16x8*)(xr + it * 512);
#pragma unroll
    for (int h = 0; h < 16; h++) {
      const u16* wr = wlds + h * Cc + lane * 8;
      float acc = 0.f;
#pragma unroll
      for (int it = 0; it < 4; it++) {
        bf16x8 wv = *(const bf16x8*)(wr + it * 512);
#pragma unroll
        for (int e = 0; e < 8; e++) acc += (float)xv[it][e] * (float)wv[e];
      }
      acc = wred(acc);
      if (lane == 0) gam[row * Hh + h] = sig_(acc + bg[h]);
    }
  }
}

// ---------------- scan phase 1 (FUSED prep, WIDENED 8 B/lane): each 32-lane
// half-wave owns one (b,h,chunk); 4 elems/lane; uint2 loads/stores; 32-wide
// reduces. Serial t-chain unchanged (loads batched 8 rows deep).
// mem written in-place over pk (same buffer; per-row read precedes write
// within the single owning half-wave).
__global__ void la_scan1(const u16* pk, const u16* __restrict__ pv,
                         const u16* __restrict__ pig,
                         const float* __restrict__ vng, const float* __restrict__ vnb,
                         const float* __restrict__ bigv,
                         u16* mem, float* gam, float* __restrict__ Ebuf) {
  const int sub  = threadIdx.x >> 5;             // 0..7 half-waves
  const int lane = threadIdx.x & 31;
  const int p = blockIdx.x * 8 + sub;            // < Bb*Hh*NCH
  const int bh = p >> 7, c = p & (NCH - 1);
  const int b = bh >> 4, h = bh & 15;
  const int t0 = c * CHK;
  const size_t rbase = (size_t)b * Tt + t0;
  const int d0 = lane * 4;
  const int c0 = h * Dd + d0;
  const size_t base = rbase * Cc + c0;
  float* gp = gam + rbase * Hh + h;
  const float4 vg = *(const float4*)&vng[d0];
  const float4 vb = *(const float4*)&vnb[d0];
  const float4 bg = *(const float4*)&bigv[c0];
  float m0 = 0.f, m1 = 0.f, m2 = 0.f, m3 = 0.f, cg = 1.f;
  for (int tb = 0; tb < CHK; tb += 8) {
    uint2 uk[8], uv[8], ui[8]; float g[8];
#pragma unroll
    for (int j = 0; j < 8; j++) {
      size_t bb = base + (size_t)(tb + j) * Cc;
      uk[j] = *(const uint2*)(pk + bb);
      uv[j] = *(const uint2*)(pv + bb);
      ui[j] = *(const uint2*)(pig + bb);
      g[j] = gp[(size_t)(tb + j) * Hh];
    }
#pragma unroll
    for (int j = 0; j < 8; j++) {
      float k0 = bf2f((u16)uk[j].x), k1 = bf2f((u16)(uk[j].x >> 16));
      float k2 = bf2f((u16)uk[j].y), k3 = bf2f((u16)(uk[j].y >> 16));
      float v0 = bf2f((u16)uv[j].x), v1 = bf2f((u16)(uv[j].x >> 16));
      float v2 = bf2f((u16)uv[j].y), v3 = bf2f((u16)(uv[j].y >> 16));
      float i0 = bf2f((u16)ui[j].x), i1 = bf2f((u16)(ui[j].x >> 16));
      float i2 = bf2f((u16)ui[j].y), i3 = bf2f((u16)(ui[j].y >> 16));
      float ks = k0*k0 + k1*k1 + k2*k2 + k3*k3;
      float s1 = v0 + v1 + v2 + v3;
      float s2 = v0*v0 + v1*v1 + v2*v2 + v3*v3;
#pragma unroll
      for (int m = 16; m; m >>= 1) {
        ks += __shfl_xor(ks, m);
        s1 += __shfl_xor(s1, m);
        s2 += __shfl_xor(s2, m);
      }
      float kn = 1.f / fmaxf(sqrtf(ks), 1e-12f);
      float mu = s1 * (1.f / Dd);
      float var = s2 * (1.f / Dd) - mu * mu;
      float rs = rsqrtf(var + EPSf);
      float vh0 = (v0 - mu) * rs * vg.x + vb.x;
      float vh1 = (v1 - mu) * rs * vg.y + vb.y;
      float vh2 = (v2 - mu) * rs * vg.z + vb.z;
      float vh3 = (v3 - mu) * rs * vg.w + vb.w;
      float kv0 = sig_(i0 + bg.x) * (k0 * kn) * vh0;
      float kv1 = sig_(i1 + bg.y) * (k1 * kn) * vh1;
      float kv2 = sig_(i2 + bg.z) * (k2 * kn) * vh2;
      float kv3 = sig_(i3 + bg.w) * (k3 * kn) * vh3;
      float gg = g[j];
      cg *= gg;
      m0 = fmaf(gg, m0, kv0);
      m1 = fmaf(gg, m1, kv1);
      m2 = fmaf(gg, m2, kv2);
      m3 = fmaf(gg, m3, kv3);
      size_t bb = base + (size_t)(tb + j) * Cc;
      uint2 om;
      om.x = (uint32_t)f2bf(m0) | ((uint32_t)f2bf(m1) << 16);
      om.y = (uint32_t)f2bf(m2) | ((uint32_t)f2bf(m3) << 16);
      *(uint2*)(mem + bb) = om;
      if (lane == 0) gp[(size_t)(tb + j) * Hh] = cg;   // cumgamma from chunk start
    }
  }
  float4 e; e.x = m0; e.y = m1; e.z = m2; e.w = m3;
  *(float4*)&Ebuf[(size_t)p * Dd + d0] = e;
}

// ---------------- scan phase 2: carry across chunks (loads batched 8) ------
__global__ void la_scan2(const float* __restrict__ Ebuf, const float* __restrict__ cumg,
                         float* __restrict__ carry) {
  const int bh = blockIdx.x;
  const int b = bh >> 4, h = bh & 15;
  const int lane = threadIdx.x;
  float S0 = 0.f, S1 = 0.f;
  for (int cb = 0; cb < NCH; cb += 8) {
    float2 E[8]; float P[8];
#pragma unroll
    for (int j = 0; j < 8; j++) {
      size_t idx = ((size_t)bh * NCH + cb + j) * Dd + lane * 2;
      E[j] = *(const float2*)&Ebuf[idx];
      P[j] = cumg[((size_t)b * Tt + (cb + j) * CHK + CHK - 1) * Hh + h];
    }
#pragma unroll
    for (int j = 0; j < 8; j++) {
      size_t idx = ((size_t)bh * NCH + cb + j) * Dd + lane * 2;
      float2 s; s.x = S0; s.y = S1;
      *(float2*)&carry[idx] = s;                 // carry INTO chunk cb+j
      S0 = fmaf(P[j], S0, E[j].x);
      S1 = fmaf(P[j], S1, E[j].y);
    }
  }
}

// ---------------- post (widened, 8-16 B/lane; R10-proven) ------------------
__global__ void la_post(const u16* mem, const u16* qp, const u16* ogp,
                        const float* __restrict__ cumg, const float* __restrict__ carry,
                        const float* __restrict__ mng, const float* __restrict__ mnb,
                        const float* __restrict__ gng, const float* __restrict__ gnb,
                        const float* __restrict__ bog, u16* outb) {
  const int wave = threadIdx.x >> 6, lane = threadIdx.x & 63;
  const int p2 = blockIdx.x * 4 + wave;          // < Mm*8
  const int row = p2 >> 3, h2 = p2 & 7;
  const int h = h2 * 2 + (lane >> 5);
  const int b = row >> 12, t = row & (Tt - 1), ch = t >> 5;  // CHK=32
  const int d0 = (lane & 31) * 4;
  const int c0 = h * Dd + d0;
  const size_t base = (size_t)row * Cc + c0;
  uint2 um = *(const uint2*)(mem + base);
  uint2 uq = *(const uint2*)(qp + base);
  uint2 uo = *(const uint2*)(ogp + base);
  float cg = cumg[(size_t)row * Hh + h];
  float4 cr = *(const float4*)&carry[(((size_t)(b * Hh + h)) * NCH + ch) * Dd + d0];
  float m0 = fmaf(cg, cr.x, bf2f((u16)um.x));
  float m1 = fmaf(cg, cr.y, bf2f((u16)(um.x >> 16)));
  float m2 = fmaf(cg, cr.z, bf2f((u16)um.y));
  float m3 = fmaf(cg, cr.w, bf2f((u16)(um.y >> 16)));
  float q0 = bf2f((u16)uq.x), q1 = bf2f((u16)(uq.x >> 16));
  float q2 = bf2f((u16)uq.y), q3 = bf2f((u16)(uq.y >> 16));
  float g0 = bf2f((u16)uo.x), g1 = bf2f((u16)(uo.x >> 16));
  float g2 = bf2f((u16)uo.y), g3 = bf2f((u16)(uo.y >> 16));
  float qs = wred32(q0*q0 + q1*q1 + q2*q2 + q3*q3);
  float s1 = wred32(m0 + m1 + m2 + m3);
  float s2 = wred32(m0*m0 + m1*m1 + m2*m2 + m3*m3);
  float qn = 1.f / fmaxf(sqrtf(qs), 1e-12f);
  float mu = s1 * (1.f / Dd);
  float var = s2 * (1.f / Dd) - mu * mu;
  float rs = rsqrtf(var + EPSf);
  float4 mg = *(const float4*)&mng[d0];
  float4 mb = *(const float4*)&mnb[d0];
  float o0 = ((m0 - mu) * rs * mg.x + mb.x) * q0 * qn;
  float o1 = ((m1 - mu) * rs * mg.y + mb.y) * q1 * qn;
  float o2 = ((m2 - mu) * rs * mg.z + mb.z) * q2 * qn;
  float o3 = ((m3 - mu) * rs * mg.w + mb.w) * q3 * qn;
  float t1 = wred32(o0 + o1 + o2 + o3);
  float t2 = wred32(o0*o0 + o1*o1 + o2*o2 + o3*o3);
  float mu2 = t1 * (1.f / Dd);
  float var2 = t2 * (1.f / Dd) - mu2 * mu2;
  float rs2 = rsqrtf(var2 + EPSf);
  float4 gg = *(const float4*)&gng[c0];
  float4 gb = *(const float4*)&gnb[c0];
  float4 bo = *(const float4*)&bog[c0];
  float y0 = ((o0 - mu2) * rs2 * gg.x + gb.x) * sig_(g0 + bo.x);
  float y1 = ((o1 - mu2) * rs2 * gg.y + gb.y) * sig_(g1 + bo.y);
  float y2 = ((o2 - mu2) * rs2 * gg.z + gb.z) * sig_(g2 + bo.z);
  float y3 = ((o3 - mu2) * rs2 * gg.w + gb.w) * sig_(g3 + bo.w);
  uint2 out;
  out.x = (uint32_t)f2bf(y0) | ((uint32_t)f2bf(y1) << 16);
  out.y = (uint32_t)f2bf(y2) | ((uint32_t)f2bf(y3) << 16);
  *(uint2*)(outb + base) = out;
}

// ---------------- GEMM: C = A @ W^T, 256x256 tile, BK=64, pipelined 4-phase
// (R2/R10 inner loop RESTORED — best measured: 318 µs merged, MfmaUtil 49.)
// R11 lesson: BK=32 halved LDS but occupancy stayed 1 block/CU — the
// limiter is REGISTERS (108 VGPR + 128 AGPR acc = 236 -> 256-quantum ->
// 8 waves/CU), not LDS. The 256^2 tile can never co-reside 2 blocks; the
// 128^2 route caps at ~912 TF (m97) < the ~980 TF this kernel delivers.
// Occupancy avenue closed; BK=64 is the efficiency point (fewer barriers,
// 16 MFMA/phase).
#define STAGE(t, j) do {                                                        \
    const u16* _s = (((j) == 0 || (j) == 2) ? Ab : Wb)                          \
                    + (((j) == 1 || (j) == 2) ? (size_t)128 * K : (size_t)0)    \
                    + soff + (size_t)(t) * 64;                                  \
    u16* _d = dbase + ((((t) & 1) * 4 + (j)) * 8192);                           \
    glds16(_s, _d);                                                             \
    glds16(_s + 8 * (size_t)K, _d + 512);                                       \
  } while (0)

#define LDFRAG(DST, NFR, SLOT, RBASE) do {                                      \
    _Pragma("unroll")                                                           \
    for (int _i = 0; _i < (NFR); ++_i)                                          \
      _Pragma("unroll")                                                         \
      for (int _ks = 0; _ks < 2; ++_ks)                                         \
        DST[_i][_ks] = *(const bf16x8*)&(SLOT)[((RBASE) + _i * 16) * 64 +       \
                         ((((lane >> 4) + _ks * 4) ^ x7) * 8)];                 \
  } while (0)

#define MM16(QM, QN, AA, BB) do {                                               \
    __builtin_amdgcn_s_setprio(1);                                              \
    _Pragma("unroll")                                                           \
    for (int _mi = 0; _mi < 4; ++_mi)                                           \
      _Pragma("unroll")                                                         \
      for (int _ni = 0; _ni < 2; ++_ni)                                         \
        _Pragma("unroll")                                                       \
        for (int _ks = 0; _ks < 2; ++_ks)                                       \
          acc[QM][QN][_mi][_ni] = __builtin_amdgcn_mfma_f32_16x16x32_bf16(      \
              AA[_mi][_ks], BB[_ni][_ks], acc[QM][QN][_mi][_ni], 0, 0, 0);      \
    __builtin_amdgcn_s_setprio(0);                                              \
  } while (0)

#define MM16_ARD(QM, QN, AA, BB, RSLOT) do {                                    \
    __builtin_amdgcn_s_setprio(1);                                              \
    _Pragma("unroll")                                                           \
    for (int _mi = 0; _mi < 4; ++_mi) {                                         \
      _Pragma("unroll")                                                         \
      for (int _ni = 0; _ni < 2; ++_ni)                                         \
        _Pragma("unroll")                                                       \
        for (int _ks = 0; _ks < 2; ++_ks)                                       \
          acc[QM][QN][_mi][_ni] = __builtin_amdgcn_mfma_f32_16x16x32_bf16(      \
              AA[_mi][_ks], BB[_ni][_ks], acc[QM][QN][_mi][_ni], 0, 0, 0);      \
      _Pragma("unroll")                                                         \
      for (int _ks = 0; _ks < 2; ++_ks)                                         \
        AA[_mi][_ks] = *(const bf16x8*)&(RSLOT)[((ra) + _mi * 16) * 64 +        \
                         ((((lane >> 4) + _ks * 4) ^ x7) * 8)];                 \
    }                                                                           \
    __builtin_amdgcn_s_setprio(0);                                              \
  } while (0)

template <int OUT_BF16>
__global__ __launch_bounds__(512, 2)
void la_gemm(const u16* __restrict__ A0, const u16* __restrict__ A1, int segA2,
             const u16* __restrict__ W0, const u16* __restrict__ W1,
             const u16* __restrict__ W2, const u16* __restrict__ W3,
             const u16* __restrict__ W4,
             void* __restrict__ C0, void* __restrict__ C1, void* __restrict__ C2,
             void* __restrict__ C3, void* __restrict__ C4, int K) {
  __shared__ u16 lds[8 * 8192];   // 128 KB
  const int tid  = threadIdx.x;
  const int lane = tid & 63;
  const int wv   = tid >> 6;      // 0..7
  const int wm = wv >> 2;         // 0..1  (M)
  const int wn = wv & 3;          // 0..3  (N)
  const int fm = lane & 15;
  const int x7 = fm & 7;
  const int seg = blockIdx.x >> 3;
  const int bn = (blockIdx.x & 7) * 256;
  const int bm = blockIdx.y * 256;
  const u16* W = seg == 0 ? W0 : seg == 1 ? W1 : seg == 2 ? W2 : seg == 3 ? W3 : W4;
  void* Co = seg == 0 ? C0 : seg == 1 ? C1 : seg == 2 ? C2 : seg == 3 ? C3 : C4;
  const u16* A = seg < segA2 ? A0 : A1;

  const u16* Ab = A + (size_t)bm * K;
  const u16* Wb = W + (size_t)bn * K;
  const size_t soff = (size_t)(wv * 16 + (lane >> 3)) * K
                      + (size_t)(((lane & 7) ^ (lane >> 3)) * 8);
  u16* const dbase = lds + wv * 1024;   // wave-uniform; HW adds lane*16B
  const int nkt = K >> 6;               // 32 for K=2048
  const int ra = wm * 64 + fm;          // A row within half (per quadrant)
  const int rb = wn * 32 + fm;          // W row within half

  f32x4 acc[2][2][4][2] = {};
  bf16x8 af[4][2], b0f[2][2], b1f[2][2];

  // prologue: tile0 all 4 half-tiles, then tile1 slots {2,1,3}
  STAGE(0, 0); STAGE(0, 1); STAGE(0, 2); STAGE(0, 3);
  __builtin_amdgcn_sched_barrier(0);    // keep tile0's 8 loads oldest
  STAGE(1, 2); STAGE(1, 1); STAGE(1, 3);
  asm volatile("s_waitcnt vmcnt(6)" ::: "memory");   // tile0 landed
  bar_();
  // pre-reads ("kt=-1 ph3"): b1 <- (t0,slot1); a <- (t0,slot2) = a1
  LDFRAG(b1f, 2, lds + 1 * 8192, rb);
  LDFRAG(af, 4, lds + 2 * 8192, ra);

  for (int kt = 0; kt < nkt; ++kt) {
    u16* const cur = lds + (kt & 1) * 4 * 8192;
    u16* const nxt = lds + ((kt & 1) ^ 1) * 4 * 8192;

    // ph0: q11 = (a1, b1); read b0 <- cur slot3; stage (kt+1, 0)
    bar_();
    LDFRAG(b0f, 2, cur + 3 * 8192, rb);
    if (kt + 1 < nkt) STAGE(kt + 1, 0);
    __builtin_amdgcn_sched_barrier(0);
    MM16(1, 1, af, b1f);

    // ph1: q10 = (a1, b0); interleaved a <- cur slot0 (a0); stage (kt+2, 2)
    bar_();
    if (kt + 2 < nkt) STAGE(kt + 2, 2);
    __builtin_amdgcn_sched_barrier(0);
    MM16_ARD(1, 0, af, b0f, cur + 0 * 8192);

    // ph2: q01 = (a0, b1); stage (kt+2, 1); counted vmcnt gate for tile kt+1
    bar_();
    if (kt + 2 < nkt) STAGE(kt + 2, 1);
    __builtin_amdgcn_sched_barrier(0);
    MM16(0, 1, af, b1f);
    if (kt < nkt - 2)       asm volatile("s_waitcnt vmcnt(4)" ::: "memory");
    else if (kt == nkt - 2) asm volatile("s_waitcnt vmcnt(0)" ::: "memory");

    // ph3: q00 = (a0, b0); read b1 <- nxt slot1; interleaved a <- nxt slot2;
    //      stage (kt+2, 3)
    bar_();
    if (kt + 1 < nkt) {
      LDFRAG(b1f, 2, nxt + 1 * 8192, rb);
      if (kt + 2 < nkt) STAGE(kt + 2, 3);
      __builtin_amdgcn_sched_barrier(0);
      MM16_ARD(0, 0, af, b0f, nxt + 2 * 8192);
    } else {
      __builtin_amdgcn_sched_barrier(0);
      MM16(0, 0, af, b0f);
    }
  }

  const int cr = (lane >> 4) * 4;
  const int cc = lane & 15;
#pragma unroll
  for (int qm = 0; qm < 2; ++qm)
#pragma unroll
    for (int qn = 0; qn < 2; ++qn)
#pragma unroll
      for (int mi = 0; mi < 4; ++mi)
#pragma unroll
        for (int ni = 0; ni < 2; ++ni)
#pragma unroll
          for (int r = 0; r < 4; ++r) {
            size_t off = (size_t)(bm + qm * 128 + wm * 64 + mi * 16 + cr + r) * Cc
                         + (bn + qn * 128 + wn * 32 + ni * 16 + cc);
            if (OUT_BF16) ((u16*)Co)[off] = f2bf(acc[qm][qn][mi][ni][r]);
            else          ((float*)Co)[off] = acc[qm][qn][mi][ni][r];
          }
}

// ---------------- launcher -------------------------------------------------
extern "C" void kernel_launch(void* const* d_in, const int* in_sizes, int n_in,
                              void* d_out, int out_size, void* d_ws, size_t ws_size,
                              hipStream_t stream) {
  (void)in_sizes; (void)n_in; (void)out_size; (void)ws_size;
  const float* x    = (const float*)d_in[0];
  const float* Wq   = (const float*)d_in[1];
  const float* Wk   = (const float*)d_in[2];
  const float* Wv   = (const float*)d_in[3];
  const float* Wo   = (const float*)d_in[4];
  const float* cw   = (const float*)d_in[5];
  const float* cb   = (const float*)d_in[6];
  const float* Wig  = (const float*)d_in[7];
  const float* big  = (const float*)d_in[8];
  const float* Wog  = (const float*)d_in[9];
  const float* bog  = (const float*)d_in[10];
  const float* Wgam = (const float*)d_in[11];
  const float* bgam = (const float*)d_in[12];
  const float* vng  = (const float*)d_in[13];
  const float* vnb  = (const float*)d_in[14];
  const float* mng  = (const float*)d_in[15];
  const float* mnb  = (const float*)d_in[16];
  const float* gng  = (const float*)d_in[17];
  const float* gnb  = (const float*)d_in[18];

  char* ws = (char*)d_ws;
  const size_t NB = (size_t)Mm * Cc * 2;          // 32 MB per bf16 activation buf
  u16* xbf   = (u16*)(ws + 0 * NB);               // x bf16 -> post out
  u16* xconv = (u16*)(ws + 1 * NB);               // silu(conv) bf16
  u16* preq  = (u16*)(ws + 2 * NB);               // q_pre (normalized in post)
  u16* prek  = (u16*)(ws + 3 * NB);               // k_pre -> mem (scan1 in-place)
  u16* prev  = (u16*)(ws + 4 * NB);               // v_pre (dead after scan1)
  u16* preig = (u16*)(ws + 5 * NB);               // Wk,Wv,Wig,Wog bf16 -> E/carry
  u16* wbf   = (u16*)(ws + 6 * NB);               // Wq bf16 -> Wo bf16 (8 MB)
  float* gam = (float*)(ws + 6 * NB + (size_t)Cc * Cc * 2);  // [Mm][Hh] -> cumg
  const size_t WE = (size_t)Cc * Cc;
  u16* wk_bf  = preig;
  u16* wv_bf  = preig + WE;
  u16* wig_bf = preig + 2 * WE;
  u16* wog_bf = preig + 3 * WE;
  float* Ebuf  = (float*)preig;                   // 2 MB (weights dead by scan1)
  float* carry = (float*)(preig + 1024 * 1024);   // 2 MB at +2 MB
  // d_out (64 MB) as scratch until the final GEMM overwrites it:
  u16* ogscr = (u16*)d_out;                       // og_pre bf16 [0, 32 MB)
  u16* igscr = (u16*)((char*)d_out + NB);         // ig_pre bf16 [32, 64 MB)

  const int WN4 = Cc * Cc / 4;
  dim3 blk(256);
  dim3 gblk(512);

  la_conv<<<Mm * Cc / 4 / 256, blk, 0, stream>>>(x, cw, cb, xbf, xconv);

  la_cvt5<<<5 * WN4 / 256, blk, 0, stream>>>(Wq, Wk, Wv, Wig, Wog,
                                             wbf, wk_bf, wv_bf, wig_bf, wog_bf, WN4);

  // merged QKV + ig/og: 5 segments x 8 col-tiles = grid.x 40, 1280 blocks
  la_gemm<1><<<dim3(40, Mm / 256), gblk, 0, stream>>>(
      xbf, xconv, 3, wbf, wk_bf, wv_bf, wig_bf, wog_bf,
      (void*)preq, (void*)prek, (void*)prev, (void*)igscr, (void*)ogscr, Cc);

  // gamma + Wo bf16 conversion (Wq slot dead after merged GEMM)
  la_gamma<<<Mm / 16, blk, 0, stream>>>(xconv, Wgam, bgam, gam, Wo, wbf);

  // fused prep+scan1 (widened): reads prek/prev/igscr, writes mem into prek
  la_scan1<<<Bb * Hh * NCH / 8, blk, 0, stream>>>(prek, prev, igscr,
                                                  vng, vnb, big, prek, gam, Ebuf);
  la_scan2<<<Bb * Hh, dim3(64), 0, stream>>>(Ebuf, gam, carry);

  // widened post: 1 half-wave per (row, head), 4 elems/lane
  la_post<<<Mm * 8 / 4, blk, 0, stream>>>(prek, preq, ogscr, gam, carry,
                                          mng, mnb, gng, gnb, bog, xbf);

  la_gemm<0><<<dim3(8, Mm / 256), gblk, 0, stream>>>(
      xbf, xbf, 5, wbf, wbf, wbf, wbf, wbf,
      d_out, d_out, d_out, d_out, d_out, Cc);
}